// Round 10
// baseline (245.705 us; speedup 1.0000x reference)
//
#include <hip/hip_runtime.h>

// MPNN_edge_sparse_ogb — round 9: R8 + MLP v2 (one-wave blocks, coalesced C-write).
//  - gather: R4/R8 half-wave/node 4-wide (BW-wall-bound, ~2.7 TB/s random 512B — leave alone)
//  - mlp: 16 nodes / 1-wave block (3125 blocks), GEMM2 -> LDS fp32 -> float4 out stores
// Pipeline: init -> count -> scan_partial -> scan_final -> fill -> gather -> mlp (7 dispatches)
// ws: zb | hp | counts | offsets | cursor | eids2[E]int2 | blockSums | w1p | w2p

constexpr int DIN  = 96;
constexpr int DDEG = 32;
constexpr int D    = 128;
constexpr int DH   = 256;
constexpr int DUP  = 128;

typedef short bf16x8 __attribute__((ext_vector_type(8)));
typedef float f32x4  __attribute__((ext_vector_type(4)));
typedef unsigned short u16x4 __attribute__((ext_vector_type(4)));

static __device__ __forceinline__ ushort f2bf(float f) {
    unsigned u = __float_as_uint(f);
    unsigned r = (u + 0x7fff + ((u >> 16) & 1)) >> 16;   // RNE
    return (ushort)r;
}
static __device__ __forceinline__ float4 bfv_to_f4(u16x4 u) {
    float4 r;
    r.x = __uint_as_float((unsigned)u.x << 16);
    r.y = __uint_as_float((unsigned)u.y << 16);
    r.z = __uint_as_float((unsigned)u.z << 16);
    r.w = __uint_as_float((unsigned)u.w << 16);
    return r;
}
static __device__ __forceinline__ int waveInclScan(int v, int lane) {
#pragma unroll
    for (int off = 1; off < 64; off <<= 1) {
        int t = __shfl_up(v, off, 64);
        if (lane >= off) v += t;
    }
    return v;
}

// ---------------------------------------------------------------- 0. init: hp pack + weight pack + zero counts
__global__ __launch_bounds__(256) void init_h_kernel(
    const float* __restrict__ x, const float* __restrict__ deg,
    const float* __restrict__ W1, const float* __restrict__ W2,
    ushort* __restrict__ hp, ushort* __restrict__ w1p, ushort* __restrict__ w2p,
    int* __restrict__ counts, int N) {
    int t = blockIdx.x * 256 + threadIdx.x;
    if (t < (N >> 2)) *reinterpret_cast<int4*>(&counts[t * 4]) = make_int4(0, 0, 0, 0);
    if (t == (N >> 2) && (N & 3)) {
        for (int i = (N & ~3); i < N; ++i) counts[i] = 0;
    }
    if (t < 32768) {
        {   // w1p[((kb*16+nb)*64+l)*8+j] = bf16(W1[kb*32+(l>>4)*8+j][nb*16+(l&15)])
            int j = t & 7, l = (t >> 3) & 63, nb = (t >> 9) & 15, kb = t >> 13;
            w1p[t] = f2bf(W1[(kb * 32 + (l >> 4) * 8 + j) * DH + nb * 16 + (l & 15)]);
        }
        {   // w2p: kb<8, nb<8
            int j = t & 7, l = (t >> 3) & 63, nb = (t >> 9) & 7, kb = t >> 12;
            w2p[t] = f2bf(W2[(kb * 32 + (l >> 4) * 8 + j) * DUP + nb * 16 + (l & 15)]);
        }
    }
    if (t >= N * 32) return;
    int n = t >> 5, c = t & 31;
    float4 v;
    if (c < 24) v = *reinterpret_cast<const float4*>(&x[(size_t)n * DIN + c * 4]);
    else        v = *reinterpret_cast<const float4*>(&deg[(size_t)n * DDEG + (c - 24) * 4]);
    u16x4 o;
    o.x = f2bf(v.x); o.y = f2bf(v.y); o.z = f2bf(v.z); o.w = f2bf(v.w);
    *reinterpret_cast<u16x4*>(&hp[(size_t)n * D + c * 4]) = o;
}

// ---------------------------------------------------------------- 1. count in-degrees
__global__ __launch_bounds__(256) void count_kernel(
    const int* __restrict__ ei, int* __restrict__ counts, int N, int E) {
    int e = blockIdx.x * 256 + threadIdx.x;
    if (e >= E) return;
    atomicAdd(&counts[ei[E + e]], 1);
}

// ---------------------------------------------------------------- 2a. per-1024-block sums
__global__ __launch_bounds__(256) void scan_partial_kernel(
    const int* __restrict__ counts, int* __restrict__ blockSums, int N) {
    const int tid = threadIdx.x;
    int base = blockIdx.x * 1024 + tid * 4;
    int4 c = make_int4(0, 0, 0, 0);
    if (base + 3 < N) c = *reinterpret_cast<const int4*>(&counts[base]);
    else if (base < N) {
        c.x = counts[base];
        if (base + 1 < N) c.y = counts[base + 1];
        if (base + 2 < N) c.z = counts[base + 2];
    }
    int s = c.x + c.y + c.z + c.w;
#pragma unroll
    for (int off = 32; off; off >>= 1) s += __shfl_xor(s, off, 64);
    __shared__ int wsum[4];
    if ((tid & 63) == 0) wsum[tid >> 6] = s;
    __syncthreads();
    if (tid == 0) blockSums[blockIdx.x] = wsum[0] + wsum[1] + wsum[2] + wsum[3];
}

// ---------------------------------------------------------------- 2b. final scan (self-computed base) -> offsets/cursor
__global__ __launch_bounds__(256) void scan_final_kernel(
    const int* __restrict__ counts, const int* __restrict__ blockSums,
    int* __restrict__ offsets, int* __restrict__ cursor, int N, int E, int nbScan) {
    const int tid = threadIdx.x, lane = tid & 63, wave = tid >> 6;
    __shared__ int sBase;
    __shared__ int wsum[4];

    if (wave == 0) {
        int v = (lane < blockIdx.x && lane < nbScan) ? blockSums[lane] : 0;
#pragma unroll
        for (int off = 32; off; off >>= 1) v += __shfl_xor(v, off, 64);
        if (lane == 0) sBase = v;
    }

    int base = blockIdx.x * 1024 + tid * 4;
    int4 c = make_int4(0, 0, 0, 0);
    if (base + 3 < N) c = *reinterpret_cast<const int4*>(&counts[base]);
    else if (base < N) {
        c.x = counts[base];
        if (base + 1 < N) c.y = counts[base + 1];
        if (base + 2 < N) c.z = counts[base + 2];
    }
    int s = c.x + c.y + c.z + c.w;
    int incl = waveInclScan(s, lane);
    if (lane == 63) wsum[wave] = incl;
    __syncthreads();
    int wb = 0;
#pragma unroll
    for (int w = 0; w < 4; ++w)
        if (w < wave) wb += wsum[w];
    int ex = sBase + wb + (incl - s);
    if (base < N)     { offsets[base]     = ex; cursor[base]     = ex; } ex += c.x;
    if (base + 1 < N) { offsets[base + 1] = ex; cursor[base + 1] = ex; } ex += c.y;
    if (base + 2 < N) { offsets[base + 2] = ex; cursor[base + 2] = ex; } ex += c.z;
    if (base + 3 < N) { offsets[base + 3] = ex; cursor[base + 3] = ex; }
    if (blockIdx.x == 0 && tid == 0) offsets[N] = E;
}

// ---------------------------------------------------------------- 3. fill CSR payload {e, src}
__global__ __launch_bounds__(256) void fill_kernel(
    const int* __restrict__ ei, int* __restrict__ cursor,
    int2* __restrict__ eids2, int E) {
    int e = blockIdx.x * 256 + threadIdx.x;
    if (e >= E) return;
    int src = ei[e];
    int dst = ei[E + e];
    int pos = atomicAdd(&cursor[dst], 1);
    eids2[pos] = make_int2(e, src);
}

// ---------------------------------------------------------------- 4. gather: half-wave/node, 4-wide unroll
__global__ __launch_bounds__(256) void gather_kernel(
    const ushort* __restrict__ hp, const float* __restrict__ ef,
    const int* __restrict__ offsets, const int2* __restrict__ eids2,
    ushort* __restrict__ zb, int N) {
    const int node = blockIdx.x * 8 + (threadIdx.x >> 5);
    if (node >= N) return;
    const int c = threadIdx.x & 31;

    float4 h = bfv_to_f4(*reinterpret_cast<const u16x4*>(&hp[(size_t)node * D + c * 4]));

    float4 acc = make_float4(0.f, 0.f, 0.f, 0.f);
    const int pEnd = offsets[node + 1];
    int p = offsets[node];

    for (; p + 4 <= pEnd; p += 4) {
        int2 i0 = eids2[p + 0];
        int2 i1 = eids2[p + 1];
        int2 i2 = eids2[p + 2];
        int2 i3 = eids2[p + 3];
        f32x4 f0 = __builtin_nontemporal_load(
            reinterpret_cast<const f32x4*>(&ef[(size_t)i0.x * D + c * 4]));
        f32x4 f1 = __builtin_nontemporal_load(
            reinterpret_cast<const f32x4*>(&ef[(size_t)i1.x * D + c * 4]));
        f32x4 f2 = __builtin_nontemporal_load(
            reinterpret_cast<const f32x4*>(&ef[(size_t)i2.x * D + c * 4]));
        f32x4 f3 = __builtin_nontemporal_load(
            reinterpret_cast<const f32x4*>(&ef[(size_t)i3.x * D + c * 4]));
        float4 h0 = bfv_to_f4(*reinterpret_cast<const u16x4*>(&hp[(size_t)i0.y * D + c * 4]));
        float4 h1 = bfv_to_f4(*reinterpret_cast<const u16x4*>(&hp[(size_t)i1.y * D + c * 4]));
        float4 h2 = bfv_to_f4(*reinterpret_cast<const u16x4*>(&hp[(size_t)i2.y * D + c * 4]));
        float4 h3 = bfv_to_f4(*reinterpret_cast<const u16x4*>(&hp[(size_t)i3.y * D + c * 4]));
        acc.x += fmaxf(f0[0] + h0.x, 0.f) + fmaxf(f1[0] + h1.x, 0.f)
               + fmaxf(f2[0] + h2.x, 0.f) + fmaxf(f3[0] + h3.x, 0.f);
        acc.y += fmaxf(f0[1] + h0.y, 0.f) + fmaxf(f1[1] + h1.y, 0.f)
               + fmaxf(f2[1] + h2.y, 0.f) + fmaxf(f3[1] + h3.y, 0.f);
        acc.z += fmaxf(f0[2] + h0.z, 0.f) + fmaxf(f1[2] + h1.z, 0.f)
               + fmaxf(f2[2] + h2.z, 0.f) + fmaxf(f3[2] + h3.z, 0.f);
        acc.w += fmaxf(f0[3] + h0.w, 0.f) + fmaxf(f1[3] + h1.w, 0.f)
               + fmaxf(f2[3] + h2.w, 0.f) + fmaxf(f3[3] + h3.w, 0.f);
    }
    for (; p < pEnd; ++p) {
        int2 i0 = eids2[p];
        f32x4 f0 = __builtin_nontemporal_load(
            reinterpret_cast<const f32x4*>(&ef[(size_t)i0.x * D + c * 4]));
        float4 h0 = bfv_to_f4(*reinterpret_cast<const u16x4*>(&hp[(size_t)i0.y * D + c * 4]));
        acc.x += fmaxf(f0[0] + h0.x, 0.f);
        acc.y += fmaxf(f0[1] + h0.y, 0.f);
        acc.z += fmaxf(f0[2] + h0.z, 0.f);
        acc.w += fmaxf(f0[3] + h0.w, 0.f);
    }
    u16x4 o;
    o.x = f2bf(h.x + acc.x);
    o.y = f2bf(h.y + acc.y);
    o.z = f2bf(h.z + acc.z);
    o.w = f2bf(h.w + acc.w);
    *reinterpret_cast<u16x4*>(&zb[(size_t)node * D + c * 4]) = o;
}

// ---------------------------------------------------------------- 5. MFMA MLP v2: 16 nodes / 1-wave block
__global__ __launch_bounds__(64) void mlp_mfma_kernel(
    const ushort* __restrict__ zb,
    const ushort* __restrict__ w1p, const float* __restrict__ b1,
    const ushort* __restrict__ w2p, const float* __restrict__ b2,
    float* __restrict__ out, int N) {
    __shared__ ushort u_lds[16][DH + 8];          // 8448 B; reused as fp32 [16][132] for C-write
    const int lane = threadIdx.x;
    const int m0 = blockIdx.x * 16;
    const int lr = lane & 15, lg = lane >> 4;

    bf16x8 a1[4];
    int rowA = m0 + lr; if (rowA > N - 1) rowA = N - 1;
    const ushort* zrow = &zb[(size_t)rowA * D + lg * 8];
#pragma unroll
    for (int kb = 0; kb < 4; ++kb)
        a1[kb] = *reinterpret_cast<const bf16x8*>(zrow + kb * 32);

    // GEMM1: u = relu(z @ W1 + b1) -> LDS bf16
#pragma unroll
    for (int nb = 0; nb < 16; ++nb) {
        f32x4 c = {0.f, 0.f, 0.f, 0.f};
#pragma unroll
        for (int kb = 0; kb < 4; ++kb) {
            bf16x8 b = *reinterpret_cast<const bf16x8*>(&w1p[((kb * 16 + nb) * 64 + lane) * 8]);
            c = __builtin_amdgcn_mfma_f32_16x16x32_bf16(a1[kb], b, c, 0, 0, 0);
        }
        float bias = b1[nb * 16 + lr];
#pragma unroll
        for (int r = 0; r < 4; ++r) {
            float v = fmaxf(c[r] + bias, 0.f);
            u_lds[lg * 4 + r][nb * 16 + lr] = f2bf(v);
        }
    }
    __syncthreads();

    bf16x8 a2[8];
#pragma unroll
    for (int kb = 0; kb < 8; ++kb)
        a2[kb] = *reinterpret_cast<const bf16x8*>(&u_lds[lr][kb * 32 + lg * 8]);
    __syncthreads();   // all u_lds reads done before fp32 overwrite

    // GEMM2: out = u @ W2 + b2 -> LDS fp32 [16][132] -> coalesced float4 stores
    float* fout = reinterpret_cast<float*>(&u_lds[0][0]);
#pragma unroll
    for (int nb = 0; nb < 8; ++nb) {
        f32x4 c = {0.f, 0.f, 0.f, 0.f};
#pragma unroll
        for (int kb = 0; kb < 8; ++kb) {
            bf16x8 b = *reinterpret_cast<const bf16x8*>(&w2p[((kb * 8 + nb) * 64 + lane) * 8]);
            c = __builtin_amdgcn_mfma_f32_16x16x32_bf16(a2[kb], b, c, 0, 0, 0);
        }
        float bias = b2[nb * 16 + lr];
#pragma unroll
        for (int r = 0; r < 4; ++r)
            fout[(lg * 4 + r) * 132 + nb * 16 + lr] = c[r] + bias;
    }
    __syncthreads();

#pragma unroll
    for (int i = 0; i < 8; ++i) {
        int idx = i * 64 + lane;        // 0..511
        int row = idx >> 5;             // 0..15
        int c4  = idx & 31;             // 0..31
        int grow = m0 + row;
        if (grow < N) {
            float4 v = *reinterpret_cast<const float4*>(&fout[row * 132 + c4 * 4]);
            *reinterpret_cast<float4*>(&out[(size_t)grow * DUP + c4 * 4]) = v;
        }
    }
}

// ---------------------------------------------------------------- launch
extern "C" void kernel_launch(void* const* d_in, const int* in_sizes, int n_in,
                              void* d_out, int out_size, void* d_ws, size_t ws_size,
                              hipStream_t stream) {
    const float* x   = (const float*)d_in[0];
    const float* dg  = (const float*)d_in[1];
    const float* ef  = (const float*)d_in[2];
    const float* W1  = (const float*)d_in[3];
    const float* b1  = (const float*)d_in[4];
    const float* W2  = (const float*)d_in[5];
    const float* b2  = (const float*)d_in[6];
    const int*   ei  = (const int*)d_in[7];
    float* out = (float*)d_out;

    const int N = in_sizes[0] / DIN;       // 50000
    const int E = in_sizes[7] / 2;         // 800000

    auto align16 = [](size_t v) { return (v + 15) & ~(size_t)15; };
    char* w = (char*)d_ws;
    ushort* zb      = (ushort*)w;  w += align16((size_t)N * D * 2);
    ushort* hp      = (ushort*)w;  w += align16((size_t)N * D * 2);
    int*   counts   = (int*)w;     w += align16((size_t)N * 4);
    int*   offsets  = (int*)w;     w += align16((size_t)(N + 1) * 4);
    int*   cursor   = (int*)w;     w += align16((size_t)N * 4);
    int2*  eids2    = (int2*)w;    w += align16((size_t)E * 8);
    int*   blockSums= (int*)w;     w += align16(64 * 4);
    ushort* w1p     = (ushort*)w;  w += align16((size_t)D * DH * 2);
    ushort* w2p     = (ushort*)w;  w += align16((size_t)DH * DUP * 2);

    const int eb = (E + 255) / 256;
    const int nbScan = (N + 1023) / 1024;   // 49

    init_h_kernel<<<(N * 32 + 255) / 256, 256, 0, stream>>>(
        x, dg, W1, W2, hp, w1p, w2p, counts, N);
    count_kernel<<<eb, 256, 0, stream>>>(ei, counts, N, E);
    scan_partial_kernel<<<nbScan, 256, 0, stream>>>(counts, blockSums, N);
    scan_final_kernel<<<nbScan, 256, 0, stream>>>(counts, blockSums, offsets, cursor, N, E, nbScan);
    fill_kernel<<<eb, 256, 0, stream>>>(ei, cursor, eids2, E);

    gather_kernel<<<(N + 7) / 8, 256, 0, stream>>>(hp, ef, offsets, eids2, zb, N);

    mlp_mfma_kernel<<<(N + 15) / 16, 64, 0, stream>>>(zb, w1p, b1, w2p, b2, out, N);
}

// Round 11
// 240.833 us; speedup vs baseline: 1.0202x; 1.0202x over previous
//
#include <hip/hip_runtime.h>

// MPNN_edge_sparse_ogb — round 10: revert to R8 (best: 239.4 µs).
// R9's 1-wave MLP regressed (+6.3 µs: 4x weight re-fetch per block, no wave overlap).
// Final structure: init(hp+wpack+zero) -> count -> scan_partial -> scan_final(self-base)
//                  -> fill -> gather (half-wave/node, 4-wide) -> mlp (64 nodes, 4 waves).
// Gather is the floor: 410 MB permutation-ordered 512B reads @ ~2.7 TB/s pattern wall
// (ILP-insensitive R3/R4/R5; write-side randomness R6/R7 strictly worse).
// ws: zb | hp | counts | offsets | cursor | eids2[E]int2 | blockSums | w1p | w2p

constexpr int DIN  = 96;
constexpr int DDEG = 32;
constexpr int D    = 128;
constexpr int DH   = 256;
constexpr int DUP  = 128;

typedef short bf16x8 __attribute__((ext_vector_type(8)));
typedef float f32x4  __attribute__((ext_vector_type(4)));
typedef unsigned short u16x4 __attribute__((ext_vector_type(4)));

static __device__ __forceinline__ ushort f2bf(float f) {
    unsigned u = __float_as_uint(f);
    unsigned r = (u + 0x7fff + ((u >> 16) & 1)) >> 16;   // RNE
    return (ushort)r;
}
static __device__ __forceinline__ float4 bfv_to_f4(u16x4 u) {
    float4 r;
    r.x = __uint_as_float((unsigned)u.x << 16);
    r.y = __uint_as_float((unsigned)u.y << 16);
    r.z = __uint_as_float((unsigned)u.z << 16);
    r.w = __uint_as_float((unsigned)u.w << 16);
    return r;
}
static __device__ __forceinline__ int waveInclScan(int v, int lane) {
#pragma unroll
    for (int off = 1; off < 64; off <<= 1) {
        int t = __shfl_up(v, off, 64);
        if (lane >= off) v += t;
    }
    return v;
}

// ---------------------------------------------------------------- 0. init: hp pack + weight pack + zero counts
__global__ __launch_bounds__(256) void init_h_kernel(
    const float* __restrict__ x, const float* __restrict__ deg,
    const float* __restrict__ W1, const float* __restrict__ W2,
    ushort* __restrict__ hp, ushort* __restrict__ w1p, ushort* __restrict__ w2p,
    int* __restrict__ counts, int N) {
    int t = blockIdx.x * 256 + threadIdx.x;
    if (t < (N >> 2)) *reinterpret_cast<int4*>(&counts[t * 4]) = make_int4(0, 0, 0, 0);
    if (t == (N >> 2) && (N & 3)) {
        for (int i = (N & ~3); i < N; ++i) counts[i] = 0;
    }
    if (t < 32768) {
        {   // w1p[((kb*16+nb)*64+l)*8+j] = bf16(W1[kb*32+(l>>4)*8+j][nb*16+(l&15)])
            int j = t & 7, l = (t >> 3) & 63, nb = (t >> 9) & 15, kb = t >> 13;
            w1p[t] = f2bf(W1[(kb * 32 + (l >> 4) * 8 + j) * DH + nb * 16 + (l & 15)]);
        }
        {   // w2p: kb<8, nb<8
            int j = t & 7, l = (t >> 3) & 63, nb = (t >> 9) & 7, kb = t >> 12;
            w2p[t] = f2bf(W2[(kb * 32 + (l >> 4) * 8 + j) * DUP + nb * 16 + (l & 15)]);
        }
    }
    if (t >= N * 32) return;
    int n = t >> 5, c = t & 31;
    float4 v;
    if (c < 24) v = *reinterpret_cast<const float4*>(&x[(size_t)n * DIN + c * 4]);
    else        v = *reinterpret_cast<const float4*>(&deg[(size_t)n * DDEG + (c - 24) * 4]);
    u16x4 o;
    o.x = f2bf(v.x); o.y = f2bf(v.y); o.z = f2bf(v.z); o.w = f2bf(v.w);
    *reinterpret_cast<u16x4*>(&hp[(size_t)n * D + c * 4]) = o;
}

// ---------------------------------------------------------------- 1. count in-degrees
__global__ __launch_bounds__(256) void count_kernel(
    const int* __restrict__ ei, int* __restrict__ counts, int N, int E) {
    int e = blockIdx.x * 256 + threadIdx.x;
    if (e >= E) return;
    atomicAdd(&counts[ei[E + e]], 1);
}

// ---------------------------------------------------------------- 2a. per-1024-block sums
__global__ __launch_bounds__(256) void scan_partial_kernel(
    const int* __restrict__ counts, int* __restrict__ blockSums, int N) {
    const int tid = threadIdx.x;
    int base = blockIdx.x * 1024 + tid * 4;
    int4 c = make_int4(0, 0, 0, 0);
    if (base + 3 < N) c = *reinterpret_cast<const int4*>(&counts[base]);
    else if (base < N) {
        c.x = counts[base];
        if (base + 1 < N) c.y = counts[base + 1];
        if (base + 2 < N) c.z = counts[base + 2];
    }
    int s = c.x + c.y + c.z + c.w;
#pragma unroll
    for (int off = 32; off; off >>= 1) s += __shfl_xor(s, off, 64);
    __shared__ int wsum[4];
    if ((tid & 63) == 0) wsum[tid >> 6] = s;
    __syncthreads();
    if (tid == 0) blockSums[blockIdx.x] = wsum[0] + wsum[1] + wsum[2] + wsum[3];
}

// ---------------------------------------------------------------- 2b. final scan (self-computed base) -> offsets/cursor
__global__ __launch_bounds__(256) void scan_final_kernel(
    const int* __restrict__ counts, const int* __restrict__ blockSums,
    int* __restrict__ offsets, int* __restrict__ cursor, int N, int E, int nbScan) {
    const int tid = threadIdx.x, lane = tid & 63, wave = tid >> 6;
    __shared__ int sBase;
    __shared__ int wsum[4];

    if (wave == 0) {
        int v = (lane < blockIdx.x && lane < nbScan) ? blockSums[lane] : 0;
#pragma unroll
        for (int off = 32; off; off >>= 1) v += __shfl_xor(v, off, 64);
        if (lane == 0) sBase = v;
    }

    int base = blockIdx.x * 1024 + tid * 4;
    int4 c = make_int4(0, 0, 0, 0);
    if (base + 3 < N) c = *reinterpret_cast<const int4*>(&counts[base]);
    else if (base < N) {
        c.x = counts[base];
        if (base + 1 < N) c.y = counts[base + 1];
        if (base + 2 < N) c.z = counts[base + 2];
    }
    int s = c.x + c.y + c.z + c.w;
    int incl = waveInclScan(s, lane);
    if (lane == 63) wsum[wave] = incl;
    __syncthreads();
    int wb = 0;
#pragma unroll
    for (int w = 0; w < 4; ++w)
        if (w < wave) wb += wsum[w];
    int ex = sBase + wb + (incl - s);
    if (base < N)     { offsets[base]     = ex; cursor[base]     = ex; } ex += c.x;
    if (base + 1 < N) { offsets[base + 1] = ex; cursor[base + 1] = ex; } ex += c.y;
    if (base + 2 < N) { offsets[base + 2] = ex; cursor[base + 2] = ex; } ex += c.z;
    if (base + 3 < N) { offsets[base + 3] = ex; cursor[base + 3] = ex; }
    if (blockIdx.x == 0 && tid == 0) offsets[N] = E;
}

// ---------------------------------------------------------------- 3. fill CSR payload {e, src}
__global__ __launch_bounds__(256) void fill_kernel(
    const int* __restrict__ ei, int* __restrict__ cursor,
    int2* __restrict__ eids2, int E) {
    int e = blockIdx.x * 256 + threadIdx.x;
    if (e >= E) return;
    int src = ei[e];
    int dst = ei[E + e];
    int pos = atomicAdd(&cursor[dst], 1);
    eids2[pos] = make_int2(e, src);
}

// ---------------------------------------------------------------- 4. gather: half-wave/node, 4-wide unroll
__global__ __launch_bounds__(256) void gather_kernel(
    const ushort* __restrict__ hp, const float* __restrict__ ef,
    const int* __restrict__ offsets, const int2* __restrict__ eids2,
    ushort* __restrict__ zb, int N) {
    const int node = blockIdx.x * 8 + (threadIdx.x >> 5);
    if (node >= N) return;
    const int c = threadIdx.x & 31;   // float4 chunk 0..31

    float4 h = bfv_to_f4(*reinterpret_cast<const u16x4*>(&hp[(size_t)node * D + c * 4]));

    float4 acc = make_float4(0.f, 0.f, 0.f, 0.f);
    const int pEnd = offsets[node + 1];
    int p = offsets[node];

    for (; p + 4 <= pEnd; p += 4) {
        int2 i0 = eids2[p + 0];
        int2 i1 = eids2[p + 1];
        int2 i2 = eids2[p + 2];
        int2 i3 = eids2[p + 3];
        f32x4 f0 = __builtin_nontemporal_load(
            reinterpret_cast<const f32x4*>(&ef[(size_t)i0.x * D + c * 4]));
        f32x4 f1 = __builtin_nontemporal_load(
            reinterpret_cast<const f32x4*>(&ef[(size_t)i1.x * D + c * 4]));
        f32x4 f2 = __builtin_nontemporal_load(
            reinterpret_cast<const f32x4*>(&ef[(size_t)i2.x * D + c * 4]));
        f32x4 f3 = __builtin_nontemporal_load(
            reinterpret_cast<const f32x4*>(&ef[(size_t)i3.x * D + c * 4]));
        float4 h0 = bfv_to_f4(*reinterpret_cast<const u16x4*>(&hp[(size_t)i0.y * D + c * 4]));
        float4 h1 = bfv_to_f4(*reinterpret_cast<const u16x4*>(&hp[(size_t)i1.y * D + c * 4]));
        float4 h2 = bfv_to_f4(*reinterpret_cast<const u16x4*>(&hp[(size_t)i2.y * D + c * 4]));
        float4 h3 = bfv_to_f4(*reinterpret_cast<const u16x4*>(&hp[(size_t)i3.y * D + c * 4]));
        acc.x += fmaxf(f0[0] + h0.x, 0.f) + fmaxf(f1[0] + h1.x, 0.f)
               + fmaxf(f2[0] + h2.x, 0.f) + fmaxf(f3[0] + h3.x, 0.f);
        acc.y += fmaxf(f0[1] + h0.y, 0.f) + fmaxf(f1[1] + h1.y, 0.f)
               + fmaxf(f2[1] + h2.y, 0.f) + fmaxf(f3[1] + h3.y, 0.f);
        acc.z += fmaxf(f0[2] + h0.z, 0.f) + fmaxf(f1[2] + h1.z, 0.f)
               + fmaxf(f2[2] + h2.z, 0.f) + fmaxf(f3[2] + h3.z, 0.f);
        acc.w += fmaxf(f0[3] + h0.w, 0.f) + fmaxf(f1[3] + h1.w, 0.f)
               + fmaxf(f2[3] + h2.w, 0.f) + fmaxf(f3[3] + h3.w, 0.f);
    }
    for (; p < pEnd; ++p) {
        int2 i0 = eids2[p];
        f32x4 f0 = __builtin_nontemporal_load(
            reinterpret_cast<const f32x4*>(&ef[(size_t)i0.x * D + c * 4]));
        float4 h0 = bfv_to_f4(*reinterpret_cast<const u16x4*>(&hp[(size_t)i0.y * D + c * 4]));
        acc.x += fmaxf(f0[0] + h0.x, 0.f);
        acc.y += fmaxf(f0[1] + h0.y, 0.f);
        acc.z += fmaxf(f0[2] + h0.z, 0.f);
        acc.w += fmaxf(f0[3] + h0.w, 0.f);
    }
    u16x4 o;
    o.x = f2bf(h.x + acc.x);
    o.y = f2bf(h.y + acc.y);
    o.z = f2bf(h.z + acc.z);
    o.w = f2bf(h.w + acc.w);
    *reinterpret_cast<u16x4*>(&zb[(size_t)node * D + c * 4]) = o;
}

// ---------------------------------------------------------------- 5. MFMA MLP: 64 nodes/block, 16/wave
__global__ __launch_bounds__(256) void mlp_mfma_kernel(
    const ushort* __restrict__ zb,
    const ushort* __restrict__ w1p, const float* __restrict__ b1,
    const ushort* __restrict__ w2p, const float* __restrict__ b2,
    float* __restrict__ out, int N) {
    __shared__ ushort u_lds[4][16][DH + 8];
    const int tid = threadIdx.x;
    const int wave = tid >> 6, lane = tid & 63;
    const int m0 = blockIdx.x * 64 + wave * 16;
    const int lr = lane & 15, lg = lane >> 4;

    bf16x8 a1[4];
    int rowA = m0 + lr; if (rowA > N - 1) rowA = N - 1;
    const ushort* zrow = &zb[(size_t)rowA * D + lg * 8];
#pragma unroll
    for (int kb = 0; kb < 4; ++kb)
        a1[kb] = *reinterpret_cast<const bf16x8*>(zrow + kb * 32);

#pragma unroll
    for (int nb = 0; nb < 16; ++nb) {
        f32x4 c = {0.f, 0.f, 0.f, 0.f};
#pragma unroll
        for (int kb = 0; kb < 4; ++kb) {
            bf16x8 b = *reinterpret_cast<const bf16x8*>(&w1p[((kb * 16 + nb) * 64 + lane) * 8]);
            c = __builtin_amdgcn_mfma_f32_16x16x32_bf16(a1[kb], b, c, 0, 0, 0);
        }
        float bias = b1[nb * 16 + lr];
#pragma unroll
        for (int r = 0; r < 4; ++r) {
            float v = fmaxf(c[r] + bias, 0.f);
            u_lds[wave][lg * 4 + r][nb * 16 + lr] = f2bf(v);
        }
    }
    __syncthreads();

    bf16x8 a2[8];
#pragma unroll
    for (int kb = 0; kb < 8; ++kb)
        a2[kb] = *reinterpret_cast<const bf16x8*>(&u_lds[wave][lr][kb * 32 + lg * 8]);

#pragma unroll
    for (int nb = 0; nb < 8; ++nb) {
        f32x4 c = {0.f, 0.f, 0.f, 0.f};
#pragma unroll
        for (int kb = 0; kb < 8; ++kb) {
            bf16x8 b = *reinterpret_cast<const bf16x8*>(&w2p[((kb * 8 + nb) * 64 + lane) * 8]);
            c = __builtin_amdgcn_mfma_f32_16x16x32_bf16(a2[kb], b, c, 0, 0, 0);
        }
        float bias = b2[nb * 16 + lr];
#pragma unroll
        for (int r = 0; r < 4; ++r) {
            int row = m0 + lg * 4 + r;
            if (row < N) out[(size_t)row * DUP + nb * 16 + lr] = c[r] + bias;
        }
    }
}

// ---------------------------------------------------------------- launch
extern "C" void kernel_launch(void* const* d_in, const int* in_sizes, int n_in,
                              void* d_out, int out_size, void* d_ws, size_t ws_size,
                              hipStream_t stream) {
    const float* x   = (const float*)d_in[0];
    const float* dg  = (const float*)d_in[1];
    const float* ef  = (const float*)d_in[2];
    const float* W1  = (const float*)d_in[3];
    const float* b1  = (const float*)d_in[4];
    const float* W2  = (const float*)d_in[5];
    const float* b2  = (const float*)d_in[6];
    const int*   ei  = (const int*)d_in[7];
    float* out = (float*)d_out;

    const int N = in_sizes[0] / DIN;       // 50000
    const int E = in_sizes[7] / 2;         // 800000

    auto align16 = [](size_t v) { return (v + 15) & ~(size_t)15; };
    char* w = (char*)d_ws;
    ushort* zb      = (ushort*)w;  w += align16((size_t)N * D * 2);
    ushort* hp      = (ushort*)w;  w += align16((size_t)N * D * 2);
    int*   counts   = (int*)w;     w += align16((size_t)N * 4);
    int*   offsets  = (int*)w;     w += align16((size_t)(N + 1) * 4);
    int*   cursor   = (int*)w;     w += align16((size_t)N * 4);
    int2*  eids2    = (int2*)w;    w += align16((size_t)E * 8);
    int*   blockSums= (int*)w;     w += align16(64 * 4);
    ushort* w1p     = (ushort*)w;  w += align16((size_t)D * DH * 2);
    ushort* w2p     = (ushort*)w;  w += align16((size_t)DH * DUP * 2);

    const int eb = (E + 255) / 256;
    const int nbScan = (N + 1023) / 1024;   // 49

    init_h_kernel<<<(N * 32 + 255) / 256, 256, 0, stream>>>(
        x, dg, W1, W2, hp, w1p, w2p, counts, N);
    count_kernel<<<eb, 256, 0, stream>>>(ei, counts, N, E);
    scan_partial_kernel<<<nbScan, 256, 0, stream>>>(counts, blockSums, N);
    scan_final_kernel<<<nbScan, 256, 0, stream>>>(counts, blockSums, offsets, cursor, N, E, nbScan);
    fill_kernel<<<eb, 256, 0, stream>>>(ei, cursor, eids2, E);

    gather_kernel<<<(N + 7) / 8, 256, 0, stream>>>(hp, ef, offsets, eids2, zb, N);

    mlp_mfma_kernel<<<(N + 63) / 64, 256, 0, stream>>>(zb, w1p, b1, w2p, b2, out, N);
}